// Round 8
// baseline (1096.833 us; speedup 1.0000x reference)
//
#include <hip/hip_runtime.h>
#include <stdint.h>

// ---------------- problem constants ----------------
#define NSTEP 100
#define FEAT  1024
#define SPIN_CAP (1 << 22)

typedef __attribute__((ext_vector_type(8)))  short short8;
typedef __attribute__((ext_vector_type(4)))  float fx4;
typedef __attribute__((ext_vector_type(16))) float fx16;

// ---------------- workspace layout (bytes) ----------------
// Exchange: parity-double-buffered, 8 groups x (32 rows x 1024 cols) bf16.
// DATA: XCD-L2-local sc0 when group is XCD-uniform (R5-proven), else sc1.
// CONTROL: agent-scope atomics at the LLC (R3/R5/R7-proven). Single adder per
// flag per phase (only wave 0 lives in the main loop) -> flag value == t+1.
// Element (group-local row m, global col c) at short index ((c>>3)*32+m)*8+(c&7).
#define OFF_EC3   0u
#define OFF_CA1   (1u << 20)
#define OFF_DRIVE (2u << 20)
#define OFF_EC3F  (OFF_DRIVE + (512u << 10))
#define OFF_CA1F  (OFF_EC3F + 4096u)
#define OFF_DRVF  (OFF_CA1F + 4096u)
#define OFF_GRP   (OFF_DRVF + 4096u)   // grpmask[8] @+0, grpcnt[8] @+512
#define WS_NEED   (OFF_GRP + 4096u)

#define GSTRIDE 32768                  // shorts per group
#define PSTRIDE (8 * GSTRIDE)          // shorts per parity buffer

// ---------------- output layout (float elems) ----------------
#define O_ACT 0
#define O_E3H 512
#define O_E5H (512 + 102400)
#define O_CAH (512 + 204800)
#define O_E3  (512 + 307200)
#define O_E5  (O_E3 + 262144)
#define O_CA  (O_E5 + 262144)

// ---------------- LDS layout (bytes) ----------------
#define LDS_W1    0
#define LDS_W2    65536
#define LDS_DRV   131072               // 100*32 f32 = 12800
#define LDS_UNI   143872
#define LDS_TOTAL 143888               // <= 163840

__device__ __forceinline__ unsigned short f2bf(float x) {
  uint32_t u = __builtin_bit_cast(uint32_t, x);
  uint32_t r = (u + 0x7FFFu + ((u >> 16) & 1u)) >> 16;   // RNE
  return (unsigned short)r;
}
__device__ __forceinline__ float sigm(float x) { return 1.0f / (1.0f + __expf(-x)); }

#define VM_DRAIN() asm volatile("s_waitcnt vmcnt(0)" ::: "memory")

__device__ __forceinline__ void llc_store_f32(float* p, float v) {
  asm volatile("global_store_dword %0, %1, off sc0 sc1" :: "v"(p), "v"(v) : "memory");
}
// bf16 exchange store (2B): uni -> XCD L2; else LLC coherent
__device__ __forceinline__ void ex_store16(void* p, unsigned short v, bool uni) {
  unsigned int vi = v;
  if (uni) asm volatile("global_store_short %0, %1, off sc0"     :: "v"(p), "v"(vi) : "memory");
  else     asm volatile("global_store_short %0, %1, off sc0 sc1" :: "v"(p), "v"(vi) : "memory");
}
// control plane: agent scope at the LLC, always
__device__ __forceinline__ void flag_add(int* p) {
  __hip_atomic_fetch_add(p, 1, __ATOMIC_RELAXED, __HIP_MEMORY_SCOPE_AGENT);
}
__device__ __forceinline__ int flag_peek(const int* p) {
  return __hip_atomic_load(p, __ATOMIC_RELAXED, __HIP_MEMORY_SCOPE_AGENT);
}
__device__ __forceinline__ void flag_wait(const int* p, int tgt) {
  int sp = 0;
  while (flag_peek(p) < tgt) {
    __builtin_amdgcn_s_sleep(2);       // backoff: cut LLC poll contention
    if (++sp > SPIN_CAP) break;        // bounded
  }
}

// ---- pipelined A-load helpers (proven asm pattern from R5/R7) ----
#define ISSUE16_UNI(buf, p)                                                   \
  _Pragma("unroll") for (int j = 0; j < 16; ++j)                              \
    asm volatile("global_load_dwordx4 %0, %1, off sc0"                        \
                 : "=v"((buf)[j]) : "v"((p) + j * 512) : "memory");
#define ISSUE16_LLC(buf, p)                                                   \
  _Pragma("unroll") for (int j = 0; j < 16; ++j)                              \
    asm volatile("global_load_dwordx4 %0, %1, off sc0 sc1"                    \
                 : "=v"((buf)[j]) : "v"((p) + j * 512) : "memory");
#define WAITVM(n, b)                                                          \
  asm volatile("s_waitcnt vmcnt(" #n ")"                                      \
    : "+v"((b)[0]), "+v"((b)[1]), "+v"((b)[2]), "+v"((b)[3]),                 \
      "+v"((b)[4]), "+v"((b)[5]), "+v"((b)[6]), "+v"((b)[7]),                 \
      "+v"((b)[8]), "+v"((b)[9]), "+v"((b)[10]), "+v"((b)[11]),               \
      "+v"((b)[12]), "+v"((b)[13]), "+v"((b)[14]), "+v"((b)[15]) :: "memory")

// Full-K 32x32 GEMM for one wave: 64 MFMAs, A pipelined 2x16, B inline from LDS
// (chunked layout, same indexing as A: elem [k=16i+8h+j][n=m] at short i*512+h*256+m*8).
template <bool UNI>
__device__ __forceinline__ void gemm_full(const short* __restrict__ ap2,
                                          const short* __restrict__ bp2,
                                          fx16& o0, fx16& o1) {
  short8 A[16], B[16];
  fx16 a0 = 0.0f, a1 = 0.0f;
  if (UNI) { ISSUE16_UNI(A, ap2); ISSUE16_UNI(B, ap2 + 16 * 512); }
  else     { ISSUE16_LLC(A, ap2); ISSUE16_LLC(B, ap2 + 16 * 512); }
  WAITVM(16, A);
#pragma unroll
  for (int j = 0; j < 16; ++j) {
    short8 b = *(const short8*)(bp2 + j * 512);
    if (j & 1) a1 = __builtin_amdgcn_mfma_f32_32x32x16_bf16(A[j], b, a1, 0, 0, 0);
    else       a0 = __builtin_amdgcn_mfma_f32_32x32x16_bf16(A[j], b, a0, 0, 0, 0);
  }
  if (UNI) { ISSUE16_UNI(A, ap2 + 32 * 512); } else { ISSUE16_LLC(A, ap2 + 32 * 512); }
  WAITVM(16, B);
#pragma unroll
  for (int j = 0; j < 16; ++j) {
    short8 b = *(const short8*)(bp2 + (16 + j) * 512);
    if (j & 1) a1 = __builtin_amdgcn_mfma_f32_32x32x16_bf16(B[j], b, a1, 0, 0, 0);
    else       a0 = __builtin_amdgcn_mfma_f32_32x32x16_bf16(B[j], b, a0, 0, 0, 0);
  }
  if (UNI) { ISSUE16_UNI(B, ap2 + 48 * 512); } else { ISSUE16_LLC(B, ap2 + 48 * 512); }
  WAITVM(16, A);
#pragma unroll
  for (int j = 0; j < 16; ++j) {
    short8 b = *(const short8*)(bp2 + (32 + j) * 512);
    if (j & 1) a1 = __builtin_amdgcn_mfma_f32_32x32x16_bf16(A[j], b, a1, 0, 0, 0);
    else       a0 = __builtin_amdgcn_mfma_f32_32x32x16_bf16(A[j], b, a0, 0, 0, 0);
  }
  WAITVM(0, B);
#pragma unroll
  for (int j = 0; j < 16; ++j) {
    short8 b = *(const short8*)(bp2 + (48 + j) * 512);
    if (j & 1) a1 = __builtin_amdgcn_mfma_f32_32x32x16_bf16(B[j], b, a1, 0, 0, 0);
    else       a0 = __builtin_amdgcn_mfma_f32_32x32x16_bf16(B[j], b, a0, 0, 0, 0);
  }
  o0 = a0; o1 = a1;
}

extern "C" __global__ void __launch_bounds__(256, 1)
hpcrnn_kernel(const int* __restrict__ cue,
              const float* __restrict__ ec3_last,
              const float* __restrict__ ec5_last,
              const float* __restrict__ ca1bias,
              const float* __restrict__ wca3ca1,
              const float* __restrict__ wec3ca1,
              const float* __restrict__ wca1ec5,
              const float* __restrict__ wca1act,
              const float* __restrict__ actbias,
              float* __restrict__ out,
              char* __restrict__ ws)
{
  extern __shared__ __attribute__((aligned(16))) char lds[];
  short* w1l  = (short*)(lds + LDS_W1);
  short* w2l  = (short*)(lds + LDS_W2);
  float* drvl = (float*)(lds + LDS_DRV);
  int*   unil = (int*)(lds + LDS_UNI);

  const int tid = threadIdx.x;
  const int bi  = blockIdx.x & 7;    // batch group; %8 == XCD residue heuristic
  const int nj  = blockIdx.x >> 3;   // N chunk (32 cols)
  const int R   = bi * 32, C = nj * 32;
  const int lane = tid & 63, wv = tid >> 6;
  const int m = lane & 31, h = lane >> 5;

  short* ec3buf = (short*)(ws + OFF_EC3);
  short* ca1buf = (short*)(ws + OFF_CA1);
  float* driveg = (float*)(ws + OFF_DRIVE);
  int*   ec3flag = (int*)(ws + OFF_EC3F);
  int*   ca1flag = (int*)(ws + OFF_CA1F);
  int*   drvflag = (int*)(ws + OFF_DRVF);
  int*   grpmask = (int*)(ws + OFF_GRP);
  int*   grpcnt  = (int*)(ws + OFF_GRP + 512);
  const int fbase = bi * 32;
  const size_t gbase = (size_t)bi * GSTRIDE;

  // ---- post group membership (XCD id), agent scope ----
  if (tid == 0) {
    int xcc;
    asm volatile("s_getreg_b32 %0, hwreg(HW_REG_XCC_ID)" : "=s"(xcc));
    __hip_atomic_fetch_or(&grpmask[bi], 1 << (xcc & 31), __ATOMIC_RELAXED, __HIP_MEMORY_SCOPE_AGENT);
    __hip_atomic_fetch_add(&grpcnt[bi], 1, __ATOMIC_RELAXED, __HIP_MEMORY_SCOPE_AGENT);
  }

  // ---- weights -> LDS, bf16, CHUNKED [g=(k>>3)][n=0..31][k&7] (all 256 threads) ----
  {
    const int c = tid & 31;
    for (int k = tid >> 5; k < FEAT; k += 8) {
      const int idx = ((k >> 3) * 32 + c) * 8 + (k & 7);
      w1l[idx] = (short)f2bf(wec3ca1[k * FEAT + C + c]);
      w2l[idx] = (short)f2bf(wca1ec5[k * FEAT + C + c]);
    }
  }

  // ---- wave0: state init (MFMA C-layout: col=m, row=(r&3)+8*(r>>2)+4h) + initial
  //      ec3 publish via LLC (sc1: readable by either consumer mode) ----
  float ec3s[16], ec5s[16], ca1s[16];
  const size_t stbase = ((size_t)((C + m) >> 3) * 32) * 8 + (m & 7);
  if (wv == 0) {
#pragma unroll
    for (int r = 0; r < 16; ++r) {
      const int row = (r & 3) + 8 * (r >> 2) + 4 * h;
      ec3s[r] = ec3_last[(size_t)(R + row) * FEAT + C + m];
      ec5s[r] = ec5_last[(size_t)(R + row) * FEAT + C + m];
      ca1s[r] = 0.0f;
      ex_store16(ec3buf + gbase + stbase + row * 8, f2bf(ec3s[r]), false);
    }
    VM_DRAIN();
    if (lane == 0) flag_add(&ec3flag[fbase + nj]);
  }

  // ---- drive: block covers its cols C..C+31 for t === bi (mod 8); the t-list is
  //      split across the 4 waves (barrier-free); per-wave drvflag add; tgt 32 ----
  {
    int cnt = 0;
    for (int t = bi; t < NSTEP; t += 8, ++cnt) {
      if ((cnt & 3) != wv) continue;
      const int col = m, kh = h;
      float part = 0.0f;
      const float tf = (float)t;
      for (int c = kh * 512; c < kh * 512 + 512; ++c) {
        float d = (float)c * (100.0f / 1023.0f) - tf;
        part += __expf(d * d * -0.02f) * wca3ca1[c * FEAT + C + col];
      }
      part += __shfl_xor(part, 32);
      if (lane < 32) llc_store_f32(driveg + t * FEAT + C + col, part);
    }
    VM_DRAIN();
    if (lane == 0) flag_add(&drvflag[nj]);
  }

  // ---- resolve group XCD-uniformity ----
  if (tid == 0) {
    flag_wait(&grpcnt[bi], 32);
    int cnt = flag_peek(&grpcnt[bi]);
    int mv  = __hip_atomic_load(&grpmask[bi], __ATOMIC_RELAXED, __HIP_MEMORY_SCOPE_AGENT);
    unil[0] = (cnt >= 32 && __popc(mv) == 1) ? 1 : 0;
  }
  __syncthreads();            // weights + drvl staging area + unil ready
  if (wv != 0) return;        // waves 1-3 done; wave0 runs the recurrence barrier-free

  const bool uni = (unil[0] != 0);
  const float biasv = ca1bias[C + m];
  const float wa0 = wca1act[(C + m) * 2 + 0];
  const float wa1 = wca1act[(C + m) * 2 + 1];

  // ---- stage drive into LDS (needs all 8 producer blocks x 4 waves) ----
  flag_wait(&drvflag[nj], 32);           // uniform: all lanes poll same addr
  for (int i = lane; i < NSTEP * 32; i += 64) {
    float v;
    asm volatile("global_load_dword %0, %1, off sc0 sc1"
                 : "=v"(v) : "v"(driveg + (i >> 5) * FEAT + C + (i & 31)) : "memory");
    asm volatile("s_waitcnt vmcnt(0)" : "+v"(v) :: "memory");
    drvl[i] = v;
  }

  const short* bp1 = w1l + h * 256 + m * 8;
  const short* bp2 = w2l + h * 256 + m * 8;

  // =================== main recurrence (single wave, no barriers) ===================
  for (int t = 0; t < NSTEP; ++t) {
    const size_t par = (size_t)(t & 1) * PSTRIDE;
    const int tgt = t + 1;

    // ---- phase 1: ca1 = relu(drive*(1+sig(ec3@w1)) - bias) ----
    if (lane < 32) flag_wait(&ec3flag[fbase + lane], tgt);
    {
      fx16 a0, a1;
      const short* ap2 = ec3buf + par + gbase + h * 256 + m * 8;
      if (uni) gemm_full<true >(ap2, bp1, a0, a1);
      else     gemm_full<false>(ap2, bp1, a0, a1);
      const float drv_t = drvl[t * 32 + m];
      short* cb = ca1buf + par + gbase + stbase;
#pragma unroll
      for (int r = 0; r < 16; ++r) {
        const int row = (r & 3) + 8 * (r >> 2) + 4 * h;
        float dot = a0[r] + a1[r];
        float v = drv_t * (1.0f + sigm(dot)) - biasv;
        ca1s[r] = fmaxf(v, 0.0f);
        ex_store16(cb + row * 8, f2bf(ca1s[r]), uni);
      }
      if (bi == 0 && lane < 32) out[O_CAH + t * FEAT + C + m] = ca1s[0];  // row 0 = reg 0, h 0
      VM_DRAIN();
      if (lane == 0) flag_add(&ca1flag[fbase + nj]);
    }

    // ---- phase 2: ec5 += ca1@w2 ; squash ; ec3 = ec5*ec3 ; cue ----
    if (lane < 32) flag_wait(&ca1flag[fbase + lane], tgt);
    {
      fx16 a0, a1;
      const short* ap2 = ca1buf + par + gbase + h * 256 + m * 8;
      if (uni) gemm_full<true >(ap2, bp2, a0, a1);
      else     gemm_full<false>(ap2, bp2, a0, a1);
#pragma unroll
      for (int r = 0; r < 16; ++r) {
        float e5 = ec5s[r] + (a0[r] + a1[r]);              // 10*TS = 1.0
        e5 = 0.69f + 0.3f * sigm(4.0f * (e5 - 0.3f));
        ec5s[r] = e5;
        ec3s[r] = e5 * ec3s[r];
      }
      if (t == 16 || t == 24) {
        const int s = (t == 24) ? 1 : 0;
#pragma unroll
        for (int r = 0; r < 16; ++r) {
          const int row = (r & 3) + 8 * (r >> 2) + 4 * h;
          int mv = cue[(size_t)(R + row) * 2048 + s * 1024 + C + m];
          if (mv) ec3s[r] = 0.4f * ec3s[r] + 0.6f;
        }
      }
      if (t < NSTEP - 1) {
        short* eb = ec3buf + (size_t)((t + 1) & 1) * PSTRIDE + gbase + stbase;
#pragma unroll
        for (int r = 0; r < 16; ++r) {
          const int row = (r & 3) + 8 * (r >> 2) + 4 * h;
          ex_store16(eb + row * 8, f2bf(ec3s[r]), uni);
        }
      }
      if (bi == 0 && lane < 32) {
        out[O_E3H + t * FEAT + C + m] = ec3s[0];
        out[O_E5H + t * FEAT + C + m] = ec5s[0];
      }
      VM_DRAIN();
      if (lane == 0 && t < NSTEP - 1) flag_add(&ec3flag[fbase + nj]);
    }
  }

  // ---- epilogue: finals + actCell (wave-local shuffle reduction) ----
#pragma unroll
  for (int r = 0; r < 16; ++r) {
    const int row = (r & 3) + 8 * (r >> 2) + 4 * h;
    out[O_E3 + (size_t)(R + row) * FEAT + C + m] = ec3s[r];
    out[O_E5 + (size_t)(R + row) * FEAT + C + m] = ec5s[r];
    out[O_CA + (size_t)(R + row) * FEAT + C + m] = ca1s[r];
    float p0 = ca1s[r] * wa0;
    float p1 = ca1s[r] * wa1;
#pragma unroll
    for (int off = 1; off < 32; off <<= 1) {
      p0 += __shfl_xor(p0, off);
      p1 += __shfl_xor(p1, off);
    }
    if (m == 0) {
      float v = p0; if (nj == 0) v += actbias[0];
      atomicAdd(&out[O_ACT + (R + row) * 2 + 0], v);
    }
    if (m == 1) {
      float v = p1; if (nj == 0) v += actbias[1];
      atomicAdd(&out[O_ACT + (R + row) * 2 + 1], v);
    }
  }
}

extern "C" void kernel_launch(void* const* d_in, const int* in_sizes, int n_in,
                              void* d_out, int out_size, void* d_ws, size_t ws_size,
                              hipStream_t stream) {
  (void)in_sizes; (void)n_in; (void)out_size;
  if (ws_size < WS_NEED) return;

  const int*   cue      = (const int*)  d_in[0];
  const float* ec3_last = (const float*)d_in[1];
  const float* ec5_last = (const float*)d_in[2];
  // d_in[3] = ca1_last: dead in the reference (overwritten before use)
  const float* ca1bias  = (const float*)d_in[4];
  const float* wca3ca1  = (const float*)d_in[5];
  const float* wec3ca1  = (const float*)d_in[6];
  const float* wca1ec5  = (const float*)d_in[7];
  const float* wca1act  = (const float*)d_in[8];
  const float* actbias  = (const float*)d_in[9];

  char* ws = (char*)d_ws;
  hipMemsetAsync(ws + OFF_EC3F, 0, 4 * 4096, stream);   // flags + rendezvous start at 0
  hipMemsetAsync(d_out, 0, 512 * sizeof(float), stream);

  hipFuncSetAttribute(reinterpret_cast<const void*>(hpcrnn_kernel),
                      hipFuncAttributeMaxDynamicSharedMemorySize, LDS_TOTAL);

  hipLaunchKernelGGL(hpcrnn_kernel, dim3(256), dim3(256), LDS_TOTAL, stream,
                     cue, ec3_last, ec5_last, ca1bias, wca3ca1, wec3ca1,
                     wca1ec5, wca1act, actbias, (float*)d_out, ws);
}